// Round 1
// baseline (173.699 us; speedup 1.0000x reference)
//
#include <hip/hip_runtime.h>

#define NN 6144
#define DD 768
#define NGROUP 2048
#define INV_T 14.285714285714286f
#define CMAX  14.285714285714286f

typedef __bf16 bf16x4_t __attribute__((ext_vector_type(4)));
typedef __bf16 bf16x8_t __attribute__((ext_vector_type(8)));
typedef float f32x4_t __attribute__((ext_vector_type(4)));

__device__ __forceinline__ void load_lds16(const void* g, void* l) {
    __builtin_amdgcn_global_load_lds((__attribute__((address_space(1))) void*)g,
                                     (__attribute__((address_space(3))) void*)l,
                                     16, 0, 0);
}

// Kernel 1: L2-normalize rows -> bf16 copy + inv_norm; also zero den_sum.
// 1536 blocks x 256 threads, one wave per row (4 rows/block).
__global__ void normalize_kernel(const float* __restrict__ feats,
                                 __bf16* __restrict__ fb,
                                 float* __restrict__ inv_norm,
                                 float* __restrict__ den_sum) {
    const int wid = threadIdx.x >> 6;
    const int lane = threadIdx.x & 63;
    const int row = blockIdx.x * 4 + wid;

    // zero den_sum: 6144 entries, 4 per block
    if (threadIdx.x < 4) den_sum[blockIdx.x * 4 + threadIdx.x] = 0.0f;

    const float4* src = (const float4*)(feats + (size_t)row * DD);
    float4 v[3];
    float ss = 0.0f;
#pragma unroll
    for (int i = 0; i < 3; ++i) {
        v[i] = src[lane + i * 64];
        ss += v[i].x * v[i].x + v[i].y * v[i].y + v[i].z * v[i].z + v[i].w * v[i].w;
    }
#pragma unroll
    for (int m = 32; m >= 1; m >>= 1) ss += __shfl_xor(ss, m);
    const float nrm = sqrtf(ss);
    const float sc = 1.0f / fmaxf(nrm, 1e-12f);

#pragma unroll
    for (int i = 0; i < 3; ++i) {
        bf16x4_t o;
        o[0] = (__bf16)(v[i].x * sc);
        o[1] = (__bf16)(v[i].y * sc);
        o[2] = (__bf16)(v[i].z * sc);
        o[3] = (__bf16)(v[i].w * sc);
        *(bf16x4_t*)(fb + (size_t)row * DD + (size_t)(lane + i * 64) * 4) = o;
    }
    if (lane == 0) inv_norm[row] = sc;
}

// Kernel 2: bf16 MFMA Gram tile + fused exp-rowsum.
// Grid: (16 col-chunks, 48 row-blocks), 256 threads (4 waves, 2x2 of 64x64).
// Per col tile: C[128x128] = f[i0..][:] * f[j0..][:]^T, K=768 in 12 steps of BK=64.
__global__ __launch_bounds__(256, 3) void gemm_expsum_kernel(
        const __bf16* __restrict__ fb, float* __restrict__ den_sum) {
    __shared__ __bf16 sA[128 * 64];
    __shared__ __bf16 sB[128 * 64];

    const int t = threadIdx.x;
    const int lane = t & 63;
    const int wid = t >> 6;
    const int wm = wid >> 1;  // wave row (0..1)
    const int wn = wid & 1;   // wave col (0..1)
    const int i0 = blockIdx.y * 128;
    const int jc = blockIdx.x;

    float rs[4][4];
#pragma unroll
    for (int a = 0; a < 4; ++a)
#pragma unroll
        for (int b = 0; b < 4; ++b) rs[a][b] = 0.0f;

    // staging mapping: per 4096B issue, thread t covers bf16[8] at row=t/8, col=(t&7)*8
    const int srow = t >> 3;
    const int scol = (t & 7) * 8;
    const __bf16* gA = fb + (size_t)(i0 + srow) * DD + scol;
    __bf16* ldsA = sA + (size_t)((wid << 6) * 8);  // wave-uniform base, +issue*256*8 later
    __bf16* ldsB = sB + (size_t)((wid << 6) * 8);

    for (int jt = 0; jt < 3; ++jt) {
        const int j0 = (jc * 3 + jt) * 128;
        const __bf16* gB = fb + (size_t)(j0 + srow) * DD + scol;

        f32x4_t acc[4][4];
        const f32x4_t zz = {0.0f, 0.0f, 0.0f, 0.0f};
#pragma unroll
        for (int mi = 0; mi < 4; ++mi)
#pragma unroll
            for (int ni = 0; ni < 4; ++ni) acc[mi][ni] = zz;

        for (int kb = 0; kb < 12; ++kb) {
            const int k0 = kb * 64;
#pragma unroll
            for (int i = 0; i < 4; ++i) {
                load_lds16(gA + (size_t)(i * 32) * DD + k0, ldsA + (size_t)(i * 256) * 8);
                load_lds16(gB + (size_t)(i * 32) * DD + k0, ldsB + (size_t)(i * 256) * 8);
            }
            __syncthreads();
#pragma unroll
            for (int kk = 0; kk < 2; ++kk) {
                const int krow = (lane >> 4) * 8 + kk * 32;
                bf16x8_t af[4], bf[4];
#pragma unroll
                for (int mi = 0; mi < 4; ++mi)
                    af[mi] = *(const bf16x8_t*)&sA[(wm * 64 + mi * 16 + (lane & 15)) * 64 + krow];
#pragma unroll
                for (int ni = 0; ni < 4; ++ni)
                    bf[ni] = *(const bf16x8_t*)&sB[(wn * 64 + ni * 16 + (lane & 15)) * 64 + krow];
#pragma unroll
                for (int mi = 0; mi < 4; ++mi)
#pragma unroll
                    for (int ni = 0; ni < 4; ++ni)
                        acc[mi][ni] = __builtin_amdgcn_mfma_f32_16x16x32_bf16(
                            af[mi], bf[ni], acc[mi][ni], 0, 0, 0);
            }
            __syncthreads();
        }

        // epilogue: C/D layout col=lane&15, row=(lane>>4)*4+reg
        const int colb = j0 + wn * 64 + (lane & 15);
        const int rowb = i0 + wm * 64 + (lane >> 4) * 4;
#pragma unroll
        for (int mi = 0; mi < 4; ++mi) {
#pragma unroll
            for (int ni = 0; ni < 4; ++ni) {
                const int col = colb + ni * 16;
#pragma unroll
                for (int r = 0; r < 4; ++r) {
                    const int row = rowb + mi * 16 + r;
                    const float v = acc[mi][ni][r] * INV_T;
                    const float e = __expf(v - CMAX);
                    rs[mi][r] += (row == col) ? 0.0f : e;
                }
            }
        }
    }

    // reduce each row-partial across the 16 lanes sharing the row, then atomicAdd
#pragma unroll
    for (int mi = 0; mi < 4; ++mi) {
#pragma unroll
        for (int r = 0; r < 4; ++r) {
            float v = rs[mi][r];
            v += __shfl_xor(v, 8);
            v += __shfl_xor(v, 4);
            v += __shfl_xor(v, 2);
            v += __shfl_xor(v, 1);
            if ((lane & 15) == 0) {
                const int row = i0 + wm * 64 + mi * 16 + (lane >> 4) * 4 + r;
                atomicAdd(&den_sum[row], v);
            }
        }
    }
}

// Kernel 3: numerator — 3 pairwise fp32 dots per group of 3 rows, one wave/group.
__global__ void numerator_kernel(const float* __restrict__ feats,
                                 const float* __restrict__ inv_norm,
                                 float* __restrict__ num) {
    const int wid = threadIdx.x >> 6;
    const int lane = threadIdx.x & 63;
    const int g = blockIdx.x * 4 + wid;
    const int r0 = g * 3;

    const float4* A = (const float4*)(feats + (size_t)r0 * DD);
    const float4* B = (const float4*)(feats + (size_t)(r0 + 1) * DD);
    const float4* C = (const float4*)(feats + (size_t)(r0 + 2) * DD);

    float d01 = 0.0f, d02 = 0.0f, d12 = 0.0f;
#pragma unroll
    for (int i = 0; i < 3; ++i) {
        const float4 a = A[lane + i * 64];
        const float4 b = B[lane + i * 64];
        const float4 c = C[lane + i * 64];
        d01 += a.x * b.x + a.y * b.y + a.z * b.z + a.w * b.w;
        d02 += a.x * c.x + a.y * c.y + a.z * c.z + a.w * c.w;
        d12 += b.x * c.x + b.y * c.y + b.z * c.z + b.w * c.w;
    }
#pragma unroll
    for (int m = 32; m >= 1; m >>= 1) {
        d01 += __shfl_xor(d01, m);
        d02 += __shfl_xor(d02, m);
        d12 += __shfl_xor(d12, m);
    }
    if (lane == 0) {
        const float s0 = inv_norm[r0], s1 = inv_norm[r0 + 1], s2 = inv_norm[r0 + 2];
        const float s01 = d01 * s0 * s1 * INV_T;
        const float s02 = d02 * s0 * s2 * INV_T;
        const float s12 = d12 * s1 * s2 * INV_T;
        // lse2(a,b) = max + log1p(exp(-|a-b|))
        num[r0]     = fmaxf(s01, s02) + log1pf(__expf(-fabsf(s01 - s02)));
        num[r0 + 1] = fmaxf(s01, s12) + log1pf(__expf(-fabsf(s01 - s12)));
        num[r0 + 2] = fmaxf(s02, s12) + log1pf(__expf(-fabsf(s02 - s12)));
    }
}

// Kernel 4: loss = mean(C + log(den_sum) - num). Single block.
__global__ void finalize_kernel(const float* __restrict__ den_sum,
                                const float* __restrict__ num,
                                float* __restrict__ out) {
    float local = 0.0f;
    for (int i = threadIdx.x; i < NN; i += 256) {
        const float den = logf(den_sum[i]) + CMAX;
        local += den - num[i];
    }
#pragma unroll
    for (int m = 32; m >= 1; m >>= 1) local += __shfl_xor(local, m);
    __shared__ float ws[4];
    if ((threadIdx.x & 63) == 0) ws[threadIdx.x >> 6] = local;
    __syncthreads();
    if (threadIdx.x == 0) out[0] = (ws[0] + ws[1] + ws[2] + ws[3]) / (float)NN;
}

extern "C" void kernel_launch(void* const* d_in, const int* in_sizes, int n_in,
                              void* d_out, int out_size, void* d_ws, size_t ws_size,
                              hipStream_t stream) {
    const float* feats = (const float*)d_in[0];
    float* out = (float*)d_out;

    char* ws = (char*)d_ws;
    __bf16* fb      = (__bf16*)ws;                               // 6144*768*2 = 9437184 B
    float* inv_norm = (float*)(ws + 9437184);                    // 24576 B
    float* den_sum  = (float*)(ws + 9437184 + 24576);            // 24576 B
    float* num      = (float*)(ws + 9437184 + 2 * 24576);        // 24576 B

    normalize_kernel<<<NN / 4, 256, 0, stream>>>(feats, fb, inv_norm, den_sum);
    gemm_expsum_kernel<<<dim3(16, 48), 256, 0, stream>>>(fb, den_sum);
    numerator_kernel<<<NGROUP / 4, 256, 0, stream>>>(feats, inv_norm, num);
    finalize_kernel<<<1, 256, 0, stream>>>(den_sum, num, out);
}

// Round 2
// 127.654 us; speedup vs baseline: 1.3607x; 1.3607x over previous
//
#include <hip/hip_runtime.h>

#define NN 6144
#define DD 768
#define NGROUP 2048
#define NB 48               // 6144 / 128 tile blocks per dim
#define NTILES 1176         // NB*(NB+1)/2 upper-triangular tiles
#define INV_T 14.285714285714286f
#define CMAX  14.285714285714286f

typedef __bf16 bf16x4_t __attribute__((ext_vector_type(4)));
typedef __bf16 bf16x8_t __attribute__((ext_vector_type(8)));
typedef float f32x4_t __attribute__((ext_vector_type(4)));

__device__ __forceinline__ void load_lds16(const void* g, void* l) {
    __builtin_amdgcn_global_load_lds((__attribute__((address_space(1))) void*)g,
                                     (__attribute__((address_space(3))) void*)l,
                                     16, 0, 0);
}

// Kernel 1: fused L2-normalize -> bf16 + numerator (3 pairwise dots per group)
// + zero den_sum. One wave per group of 3 rows; 512 blocks x 256 threads.
__global__ void norm_num_kernel(const float* __restrict__ feats,
                                __bf16* __restrict__ fb,
                                float* __restrict__ num,
                                float* __restrict__ den_sum) {
    const int wid = threadIdx.x >> 6;
    const int lane = threadIdx.x & 63;
    const int g = blockIdx.x * 4 + wid;
    const int r0 = g * 3;

    if (threadIdx.x < 12) den_sum[blockIdx.x * 12 + threadIdx.x] = 0.0f;

    const float4* A = (const float4*)(feats + (size_t)r0 * DD);        // row r0
    const float4* B = (const float4*)(feats + (size_t)(r0 + 1) * DD);  // row r0+1
    const float4* C = (const float4*)(feats + (size_t)(r0 + 2) * DD);  // row r0+2

    float4 va[3], vb[3], vc[3];
    float ss0 = 0.f, ss1 = 0.f, ss2 = 0.f, d01 = 0.f, d02 = 0.f, d12 = 0.f;
#pragma unroll
    for (int i = 0; i < 3; ++i) {
        va[i] = A[lane + i * 64];
        vb[i] = B[lane + i * 64];
        vc[i] = C[lane + i * 64];
        ss0 += va[i].x * va[i].x + va[i].y * va[i].y + va[i].z * va[i].z + va[i].w * va[i].w;
        ss1 += vb[i].x * vb[i].x + vb[i].y * vb[i].y + vb[i].z * vb[i].z + vb[i].w * vb[i].w;
        ss2 += vc[i].x * vc[i].x + vc[i].y * vc[i].y + vc[i].z * vc[i].z + vc[i].w * vc[i].w;
        d01 += va[i].x * vb[i].x + va[i].y * vb[i].y + va[i].z * vb[i].z + va[i].w * vb[i].w;
        d02 += va[i].x * vc[i].x + va[i].y * vc[i].y + va[i].z * vc[i].z + va[i].w * vc[i].w;
        d12 += vb[i].x * vc[i].x + vb[i].y * vc[i].y + vb[i].z * vc[i].z + vb[i].w * vc[i].w;
    }
#pragma unroll
    for (int m = 32; m >= 1; m >>= 1) {
        ss0 += __shfl_xor(ss0, m);
        ss1 += __shfl_xor(ss1, m);
        ss2 += __shfl_xor(ss2, m);
        d01 += __shfl_xor(d01, m);
        d02 += __shfl_xor(d02, m);
        d12 += __shfl_xor(d12, m);
    }
    const float s0 = 1.0f / fmaxf(sqrtf(ss0), 1e-12f);
    const float s1 = 1.0f / fmaxf(sqrtf(ss1), 1e-12f);
    const float s2 = 1.0f / fmaxf(sqrtf(ss2), 1e-12f);

#pragma unroll
    for (int i = 0; i < 3; ++i) {
        bf16x4_t o0, o1, o2;
        o0[0] = (__bf16)(va[i].x * s0); o0[1] = (__bf16)(va[i].y * s0);
        o0[2] = (__bf16)(va[i].z * s0); o0[3] = (__bf16)(va[i].w * s0);
        o1[0] = (__bf16)(vb[i].x * s1); o1[1] = (__bf16)(vb[i].y * s1);
        o1[2] = (__bf16)(vb[i].z * s1); o1[3] = (__bf16)(vb[i].w * s1);
        o2[0] = (__bf16)(vc[i].x * s2); o2[1] = (__bf16)(vc[i].y * s2);
        o2[2] = (__bf16)(vc[i].z * s2); o2[3] = (__bf16)(vc[i].w * s2);
        const size_t cofs = (size_t)(lane + i * 64) * 4;
        *(bf16x4_t*)(fb + (size_t)r0 * DD + cofs) = o0;
        *(bf16x4_t*)(fb + (size_t)(r0 + 1) * DD + cofs) = o1;
        *(bf16x4_t*)(fb + (size_t)(r0 + 2) * DD + cofs) = o2;
    }

    if (lane == 0) {
        const float s01 = d01 * s0 * s1 * INV_T;
        const float s02 = d02 * s0 * s2 * INV_T;
        const float s12 = d12 * s1 * s2 * INV_T;
        // lse2(a,b) = max + log1p(exp(-|a-b|))
        num[r0]     = fmaxf(s01, s02) + log1pf(__expf(-fabsf(s01 - s02)));
        num[r0 + 1] = fmaxf(s01, s12) + log1pf(__expf(-fabsf(s01 - s12)));
        num[r0 + 2] = fmaxf(s02, s12) + log1pf(__expf(-fabsf(s02 - s12)));
    }
}

// Kernel 2: upper-triangular bf16 MFMA Gram tiles + fused exp row/col sums.
// 1176 blocks (one 128x128 tile each), 256 threads (2x2 waves of 64x64).
// LDS XOR-swizzled: lane loads global chunk (t&7)^((t>>3)&7); reader XORs
// k-chunk with lane&7 -> 2-way bank aliasing (free) instead of 16-way.
__global__ __launch_bounds__(256, 5) void gemm_expsum_kernel(
        const __bf16* __restrict__ fb, float* __restrict__ den_sum) {
    __shared__ __bf16 sA[128 * 64];
    __shared__ __bf16 sB[128 * 64];

    // triangular index -> (bi, bj), bi <= bj
    int rem = blockIdx.x;
    int bi = 0, rowlen = NB;
    while (rem >= rowlen) { rem -= rowlen; rowlen--; bi++; }
    const int bj = bi + rem;
    const bool isdiag = (bi == bj);
    const int i0 = bi * 128;
    const int j0 = bj * 128;

    const int t = threadIdx.x;
    const int lane = t & 63;
    const int wid = t >> 6;
    const int wm = wid >> 1;  // wave row (0..1)
    const int wn = wid & 1;   // wave col (0..1)

    // staging: thread t covers global (row=t>>3 (+32/issue), chunk=(t&7)^((t>>3)&7))
    const int srow = t >> 3;
    const int scol = ((t & 7) ^ (srow & 7)) * 8;
    const __bf16* gA = fb + (size_t)(i0 + srow) * DD + scol;
    const __bf16* gB = fb + (size_t)(j0 + srow) * DD + scol;
    __bf16* ldsA = sA + (size_t)((wid << 6) * 8);  // wave-uniform base
    __bf16* ldsB = sB + (size_t)((wid << 6) * 8);

    f32x4_t acc[4][4];
    const f32x4_t zz = {0.0f, 0.0f, 0.0f, 0.0f};
#pragma unroll
    for (int mi = 0; mi < 4; ++mi)
#pragma unroll
        for (int ni = 0; ni < 4; ++ni) acc[mi][ni] = zz;

    for (int kb = 0; kb < 12; ++kb) {
        const int k0 = kb * 64;
#pragma unroll
        for (int i = 0; i < 4; ++i) {
            load_lds16(gA + (size_t)(i * 32) * DD + k0, ldsA + (size_t)(i * 256) * 8);
            load_lds16(gB + (size_t)(i * 32) * DD + k0, ldsB + (size_t)(i * 256) * 8);
        }
        __syncthreads();
#pragma unroll
        for (int kk = 0; kk < 2; ++kk) {
            const int kx = (((lane >> 4) + kk * 4) ^ (lane & 7)) * 8;  // swizzled chunk
            bf16x8_t af[4], bfr[4];
#pragma unroll
            for (int mi = 0; mi < 4; ++mi)
                af[mi] = *(const bf16x8_t*)&sA[(wm * 64 + mi * 16 + (lane & 15)) * 64 + kx];
#pragma unroll
            for (int ni = 0; ni < 4; ++ni)
                bfr[ni] = *(const bf16x8_t*)&sB[(wn * 64 + ni * 16 + (lane & 15)) * 64 + kx];
#pragma unroll
            for (int mi = 0; mi < 4; ++mi)
#pragma unroll
                for (int ni = 0; ni < 4; ++ni)
                    acc[mi][ni] = __builtin_amdgcn_mfma_f32_16x16x32_bf16(
                        af[mi], bfr[ni], acc[mi][ni], 0, 0, 0);
        }
        __syncthreads();
    }

    // Epilogue. C/D layout: col=lane&15 (+ni*16), row=(lane>>4)*4+reg (+mi*16).
    const int colb = j0 + wn * 64 + (lane & 15);
    const int rowb = i0 + wm * 64 + ((lane >> 4) << 2);
    float cs[4] = {0.f, 0.f, 0.f, 0.f};
#pragma unroll
    for (int mi = 0; mi < 4; ++mi) {
        float rsv[4] = {0.f, 0.f, 0.f, 0.f};
#pragma unroll
        for (int ni = 0; ni < 4; ++ni) {
            const int col = colb + ni * 16;
#pragma unroll
            for (int r = 0; r < 4; ++r) {
                const int row = rowb + mi * 16 + r;
                const float v = acc[mi][ni][r] * INV_T;
                float e = __expf(v - CMAX);
                if (isdiag && row == col) e = 0.0f;
                rsv[r] += e;
                cs[ni] += e;
            }
        }
        // row-sum: 16 lanes sharing a row are lane&15 = 0..15 (same lane>>4)
#pragma unroll
        for (int r = 0; r < 4; ++r) {
            float v = rsv[r];
            v += __shfl_xor(v, 8);
            v += __shfl_xor(v, 4);
            v += __shfl_xor(v, 2);
            v += __shfl_xor(v, 1);
            if ((lane & 15) == 0) atomicAdd(&den_sum[rowb + mi * 16 + r], v);
        }
    }
    if (!isdiag) {
        // col-sum: 4 lanes sharing a col are lane>>4 = 0..3 (same lane&15)
#pragma unroll
        for (int ni = 0; ni < 4; ++ni) {
            float v = cs[ni];
            v += __shfl_xor(v, 16);
            v += __shfl_xor(v, 32);
            if ((lane >> 4) == 0) atomicAdd(&den_sum[colb + ni * 16], v);
        }
    }
}

// Kernel 3: loss = mean(C + log(den_sum) - num). Single block.
__global__ void finalize_kernel(const float* __restrict__ den_sum,
                                const float* __restrict__ num,
                                float* __restrict__ out) {
    float local = 0.0f;
    for (int i = threadIdx.x; i < NN; i += 256) {
        local += logf(den_sum[i]) + CMAX - num[i];
    }
#pragma unroll
    for (int m = 32; m >= 1; m >>= 1) local += __shfl_xor(local, m);
    __shared__ float ws[4];
    if ((threadIdx.x & 63) == 0) ws[threadIdx.x >> 6] = local;
    __syncthreads();
    if (threadIdx.x == 0) out[0] = (ws[0] + ws[1] + ws[2] + ws[3]) / (float)NN;
}

extern "C" void kernel_launch(void* const* d_in, const int* in_sizes, int n_in,
                              void* d_out, int out_size, void* d_ws, size_t ws_size,
                              hipStream_t stream) {
    const float* feats = (const float*)d_in[0];
    float* out = (float*)d_out;

    char* ws = (char*)d_ws;
    __bf16* fb     = (__bf16*)ws;                        // 6144*768*2 = 9437184 B
    float* num     = (float*)(ws + 9437184);             // 24576 B
    float* den_sum = (float*)(ws + 9437184 + 24576);     // 24576 B

    norm_num_kernel<<<NGROUP / 4, 256, 0, stream>>>(feats, fb, num, den_sum);
    gemm_expsum_kernel<<<NTILES, 256, 0, stream>>>(fb, den_sum);
    finalize_kernel<<<1, 256, 0, stream>>>(den_sum, num, out);
}